// Round 5
// baseline (240.049 us; speedup 1.0000x reference)
//
#include <hip/hip_runtime.h>
#include <hip/hip_bf16.h>
#include <cstddef>

// Problem constants (from reference setup_inputs)
#define BB 16
#define CC 192
#define HH 64
#define WW 64
#define LL 4096   // H*W
#define DTR 12    // dt_rank
#define KK 14     // dt_rank + 2*d_state, d_state = 1

__device__ __forceinline__ float silu_f(float v) {
  return v / (1.f + __expf(-v));
}

// ---------------------------------------------------------------------------
// K0: zero xdbl (3.67 MB) so proj blocks can atomicAdd their half-channel
// partial sums. 896 blocks x 256 threads x 1 float4 = exactly BB*KK*LL floats.
// ---------------------------------------------------------------------------
__global__ __launch_bounds__(256) void zero_kernel(float4* __restrict__ p) {
  p[blockIdx.x * 256 + threadIdx.x] = make_float4(0.f, 0.f, 0.f, 0.f);
}

// ---------------------------------------------------------------------------
// K1: depthwise 5x5 conv (SAME, zero pad) + bias + SiLU — LDS-free.
// One block (4 waves) per (b,c) plane; wave w owns output rows 16w..16w+15.
// Lane = x column. PRELOAD all 20 input rows (2-row halo each side) into
// registers (20 loads in flight), then: 4 shuffles per row + ring of 5
// output-row accumulators with static indices.
// REVERTED byte-identical to the R0/R1 known-good version: the R4 fusion
// (2-row strips) cost 3x halo over-fetch + serial 24-channel chains.
// ---------------------------------------------------------------------------
__global__ __launch_bounds__(256) void conv_silu_kernel(
    const float* __restrict__ x, const float* __restrict__ cw,
    const float* __restrict__ cb, float* __restrict__ xs) {
  const int bc = blockIdx.x;           // b*CC + c
  const int c = bc % CC;
  const int tid = threadIdx.x;
  const int lane = tid & 63;           // x column 0..63
  const int wv = tid >> 6;             // wave 0..3
  const int oy0 = wv * 16;             // first output row of this wave

  float w[25];
#pragma unroll
  for (int k = 0; k < 25; ++k) w[k] = cw[c * 25 + k];
  const float bias = cb[c];

  const float* xp = x + (size_t)bc * LL + lane;
  float* op = xs + (size_t)bc * LL + lane;

  // preload 20 rows (wave-uniform predication; all loads issue up front)
  float rv[20];
#pragma unroll
  for (int r = 0; r < 20; ++r) {
    const int gr = oy0 + r - 2;
    float v = 0.f;
    if ((unsigned)gr < 64u) v = xp[gr * 64];
    rv[r] = v;
  }

  float acc[5];
#pragma unroll
  for (int i = 0; i < 5; ++i) acc[i] = 0.f;

  // input row gr = oy0 + r - 2; output row y = oy0 + (r - ky).
  // y in-wave iff 0 <= r-ky < 16 (static). Row oy0+r-4 completes at iter r.
#pragma unroll
  for (int r = 0; r < 20; ++r) {
    float v = rv[r];
    float vm2 = __shfl_up(v, 2u, 64);
    float vm1 = __shfl_up(v, 1u, 64);
    float vp1 = __shfl_down(v, 1u, 64);
    float vp2 = __shfl_down(v, 2u, 64);
    if (lane < 2) vm2 = 0.f;
    if (lane < 1) vm1 = 0.f;
    if (lane > 62) vp1 = 0.f;
    if (lane > 61) vp2 = 0.f;
    float t[5] = {vm2, vm1, v, vp1, vp2};
#pragma unroll
    for (int ky = 0; ky < 5; ++ky) {
      if (r >= ky && (r - ky) < 16) {        // static under unroll
        float s = acc[(r - ky) % 5];
#pragma unroll
        for (int kx = 0; kx < 5; ++kx) s += w[ky * 5 + kx] * t[kx];
        acc[(r - ky) % 5] = s;
      }
    }
    if (r >= 4) {                            // static under unroll
      const int yf = oy0 + r - 4;
      float a = acc[(r - 4) % 5] + bias;
      op[yf * 64] = silu_f(a);
      acc[(r - 4) % 5] = 0.f;
    }
  }
}

// ---------------------------------------------------------------------------
// K2: x_dbl[b][k][l] += sum_c x_proj_w[k][c] * xs[b][c][l]   (k = 0..13)
// Occupancy fix vs R1: the old 512-block grid hard-capped occupancy at
// 16 waves/CU and its 59 KB part[8] LDS at 2 blocks/CU. Now: grid
// (32 strips, 16 b, 2 channel-halves) = 1024 blocks x 8 waves = 32 waves/CU
// requested; wave g covers 12 channels; cross-wave reduction via 7 KB LDS
// atomicAdd tile; block's half-sum folded into xdbl by global atomicAdd
// (pre-zeroed by K0). Reassociation noise ~1e-6 vs 2^-7 tolerance.
// ---------------------------------------------------------------------------
__global__ __launch_bounds__(512) void proj_kernel(
    const float* __restrict__ xs, const float* __restrict__ xpw,
    float* __restrict__ xdbl) {
  const int b = blockIdx.y;
  const int l0 = blockIdx.x * 128;
  const int half = blockIdx.z;         // 0,1: channels half*96 .. half*96+95
  const int tid = threadIdx.x;
  const int lane = tid & 63;
  const int g = tid >> 6;              // wave id, 0..7

  __shared__ float part[KK][128];      // 7 KB
  for (int i = tid; i < KK * 128; i += 512) ((float*)part)[i] = 0.f;
  __syncthreads();

  float2 acc[KK];
#pragma unroll
  for (int k = 0; k < KK; ++k) acc[k] = make_float2(0.f, 0.f);

  const int c0 = half * 96 + g * 12;
  const float* bp = xs + ((size_t)(b * CC + c0)) * LL + l0 + lane * 2;
#pragma unroll 4
  for (int cc = 0; cc < 12; ++cc) {
    float2 v = *(const float2*)(bp + (size_t)cc * LL);
    const int c = c0 + cc;             // wave-uniform -> scalar weight loads
#pragma unroll
    for (int k = 0; k < KK; ++k) {
      float wv = xpw[k * CC + c];
      acc[k].x += wv * v.x;
      acc[k].y += wv * v.y;
    }
  }
#pragma unroll
  for (int k = 0; k < KK; ++k) {
    atomicAdd(&part[k][lane * 2], acc[k].x);
    atomicAdd(&part[k][lane * 2 + 1], acc[k].y);
  }
  __syncthreads();

  for (int idx = tid; idx < KK * 128; idx += 512) {
    const int k = idx >> 7, ln = idx & 127;
    atomicAdd(&xdbl[((size_t)b * KK + k) * LL + l0 + ln], part[k][ln]);
  }
}

// ---------------------------------------------------------------------------
// K3 (v3): fused dt-projection + softplus + selective scan + output.
// 4 waves per (b,c); wave owns a 1024-l segment = 4 chunks of 256
// (lane owns 4 contiguous l's per chunk — perfectly coalesced float4).
// Same math as before, REORDERED for ILP (old version: 4 serial chunks,
// each with a 6-step ds_permute scan -> ~1100-cycle serial path, 41 us at
// VALUBusy 50%, HBM 27%):
//   Phase 1 (per chunk): consume the 12 dts planes incrementally into z4,
//     softplus -> a,be; walk chunk-LOCAL (P,h); emit per-element
//     alpha = P_local*C, beta = h_local*C + x*D  (y = alpha*G + beta).
//     Retains only alpha/beta[16] + 2 aggregate regs per chunk.
//   Phase 2: the FOUR chunks' 6-step wave-scans run manually interleaved
//     in lockstep — 4 independent shuffle chains hide each other's DS
//     latency (serial path ~4x shorter; same total shuffle count).
//   Phase 3: chain chunk totals (3 wave-uniform FMAs) -> per-chunk
//     lane-entry (Pe,he); LDS-exchange wave totals; carry fold.
//   Phase 4: G = Pe*carry + he; y = alpha*G + beta; float4 stores.
// ---------------------------------------------------------------------------
__global__ __launch_bounds__(256) void scan_kernel(
    const float* __restrict__ xs, const float* __restrict__ xdbl,
    const float* __restrict__ dtw, const float* __restrict__ dtb,
    const float* __restrict__ A_logs, const float* __restrict__ Ds,
    float* __restrict__ y) {
  const int bc = blockIdx.x;
  const int b = bc / CC;
  const int c = bc - b * CC;
  const int tid = threadIdx.x;
  const int lane = tid & 63;
  const int wv = tid >> 6;  // wave 0..3, owns segment [1024*wv, 1024*wv+1023]

  const float Ac = -__expf(A_logs[c]);  // d_state = 1
  const float Dc = Ds[c];
  float dw[DTR];
#pragma unroll
  for (int r = 0; r < DTR; ++r) dw[r] = dtw[c * DTR + r];
  const float db = dtb[c];

  const float* xp = xs + (size_t)bc * LL;
  const float* xb = xdbl + (size_t)b * KK * LL;
  float* yp = y + (size_t)bc * LL;

  __shared__ float segA[4];
  __shared__ float segB[4];

  float alpha[16], beta[16];   // static indices only (full unroll)
  float aggA[4], aggB[4];
  float av4[4][4];             // per-chunk a's kept for nothing — NOT kept; see below

  // ---- phase 1: per-chunk local scan, emit alpha/beta + aggregates ----
#pragma unroll
  for (int ck = 0; ck < 4; ++ck) {
    const int base = wv * 1024 + ck * 256 + lane * 4;
    const float4 x4 = *(const float4*)(xp + base);
    const float4 B4 = *(const float4*)(xb + 12 * LL + base);
    const float4 C4 = *(const float4*)(xb + 13 * LL + base);
    // dt-projection consumed incrementally: one dr plane live at a time
    float z4x = db, z4y = db, z4z = db, z4w = db;
#pragma unroll
    for (int r = 0; r < DTR; ++r) {
      const float4 d4 = *(const float4*)(xb + r * LL + base);
      z4x += dw[r] * d4.x;
      z4y += dw[r] * d4.y;
      z4z += dw[r] * d4.z;
      z4w += dw[r] * d4.w;
    }
    float zz[4] = {z4x, z4y, z4z, z4w};
    float Pl = 1.f, hl = 0.f;
#pragma unroll
    for (int q = 0; q < 4; ++q) {
      const float z = zz[q];
      const float delta = (z > 15.f) ? z : __logf(1.f + __expf(z));
      const float a = __expf(delta * Ac);
      const float be = delta * ((&B4.x)[q]) * ((&x4.x)[q]);
      hl = a * hl + be;
      Pl = Pl * a;
      alpha[ck * 4 + q] = Pl * ((&C4.x)[q]);
      beta[ck * 4 + q] = hl * ((&C4.x)[q]) + ((&x4.x)[q]) * Dc;
      (void)av4;
    }
    aggA[ck] = Pl;
    aggB[ck] = hl;
  }

  // ---- phase 2: 4 chunk wave-scans interleaved in lockstep ----
  float iA[4], iB[4];
#pragma unroll
  for (int ck = 0; ck < 4; ++ck) { iA[ck] = aggA[ck]; iB[ck] = aggB[ck]; }
#pragma unroll
  for (int s = 1; s < 64; s <<= 1) {
    float pA[4], pB[4];
#pragma unroll
    for (int ck = 0; ck < 4; ++ck) {
      pA[ck] = __shfl_up(iA[ck], (unsigned)s, 64);
      pB[ck] = __shfl_up(iB[ck], (unsigned)s, 64);
    }
    if (lane >= s) {
#pragma unroll
      for (int ck = 0; ck < 4; ++ck) {
        iB[ck] = iA[ck] * pB[ck] + iB[ck];
        iA[ck] = iA[ck] * pA[ck];
      }
    }
  }
  float eA[4], eB[4], tA[4], tB[4];
#pragma unroll
  for (int ck = 0; ck < 4; ++ck) {
    eA[ck] = __shfl_up(iA[ck], 1u, 64);
    eB[ck] = __shfl_up(iB[ck], 1u, 64);
    if (lane == 0) { eA[ck] = 1.f; eB[ck] = 0.f; }
    tA[ck] = __shfl(iA[ck], 63, 64);
    tB[ck] = __shfl(iB[ck], 63, 64);
  }

  // ---- phase 3: chain chunk totals; lane-entry (Pe,he) per chunk ----
  float Pe[4], he[4];
  float SP = 1.f, Sh = 0.f;   // segment state at current chunk entry
#pragma unroll
  for (int ck = 0; ck < 4; ++ck) {
    Pe[ck] = SP * eA[ck];
    he[ck] = eA[ck] * Sh + eB[ck];
    Sh = tA[ck] * Sh + tB[ck];
    SP = SP * tA[ck];
  }

  if (lane == 0) { segA[wv] = SP; segB[wv] = Sh; }
  __syncthreads();
  float carry = 0.f;
  for (int i = 0; i < wv; ++i) carry = segA[i] * carry + segB[i];

  // ---- phase 4: epilogue ----
#pragma unroll
  for (int ck = 0; ck < 4; ++ck) {
    const float G = Pe[ck] * carry + he[ck];
    const int base = wv * 1024 + ck * 256 + lane * 4;
    float4 o;
    o.x = alpha[ck * 4 + 0] * G + beta[ck * 4 + 0];
    o.y = alpha[ck * 4 + 1] * G + beta[ck * 4 + 1];
    o.z = alpha[ck * 4 + 2] * G + beta[ck * 4 + 2];
    o.w = alpha[ck * 4 + 3] * G + beta[ck * 4 + 3];
    *(float4*)(yp + base) = o;
  }
}

// ---------------------------------------------------------------------------
extern "C" void kernel_launch(void* const* d_in, const int* in_sizes, int n_in,
                              void* d_out, int out_size, void* d_ws,
                              size_t ws_size, hipStream_t stream) {
  const float* x        = (const float*)d_in[0];
  const float* conv_w   = (const float*)d_in[1];
  const float* conv_b   = (const float*)d_in[2];
  const float* x_proj_w = (const float*)d_in[3];
  const float* dt_w     = (const float*)d_in[4];
  const float* dt_b     = (const float*)d_in[5];
  const float* A_logs   = (const float*)d_in[6];
  const float* Ds       = (const float*)d_in[7];
  float* out = (float*)d_out;

  char* ws = (char*)d_ws;
  const size_t plane_bytes = (size_t)BB * CC * LL * sizeof(float);  // 50.3 MB
  float* xs   = (float*)ws;
  float* xdbl = (float*)(ws + plane_bytes);  // BB*KK*LL floats = 3.67 MB

  zero_kernel<<<dim3(BB * KK * LL / 1024), 256, 0, stream>>>((float4*)xdbl);
  conv_silu_kernel<<<dim3(BB * CC), 256, 0, stream>>>(x, conv_w, conv_b, xs);
  proj_kernel<<<dim3(LL / 128, BB, 2), 512, 0, stream>>>(xs, x_proj_w, xdbl);
  scan_kernel<<<dim3(BB * CC), 256, 0, stream>>>(xs, xdbl, dt_w, dt_b,
                                                 A_logs, Ds, out);
}

// Round 7
// 204.837 us; speedup vs baseline: 1.1719x; 1.1719x over previous
//
#include <hip/hip_runtime.h>
#include <hip/hip_bf16.h>
#include <cstddef>

// Problem constants (from reference setup_inputs)
#define BB 16
#define CC 192
#define HH 64
#define WW 64
#define LL 4096   // H*W
#define DTR 12    // dt_rank
#define KK 14     // dt_rank + 2*d_state, d_state = 1

__device__ __forceinline__ float silu_f(float v) {
  return v / (1.f + __expf(-v));
}

// ---------------------------------------------------------------------------
// K1: depthwise 5x5 conv (SAME, zero pad) + bias + SiLU — LDS-free.
// One block (4 waves) per (b,c) plane; wave w owns output rows 16w..16w+15.
// Lane = x column. PRELOAD all 20 input rows (2-row halo each side) into
// registers (20 loads in flight), then: 4 shuffles per row + ring of 5
// output-row accumulators with static indices.  (known-good, unchanged)
// ---------------------------------------------------------------------------
__global__ __launch_bounds__(256) void conv_silu_kernel(
    const float* __restrict__ x, const float* __restrict__ cw,
    const float* __restrict__ cb, float* __restrict__ xs) {
  const int bc = blockIdx.x;           // b*CC + c
  const int c = bc % CC;
  const int tid = threadIdx.x;
  const int lane = tid & 63;           // x column 0..63
  const int wv = tid >> 6;             // wave 0..3
  const int oy0 = wv * 16;             // first output row of this wave

  float w[25];
#pragma unroll
  for (int k = 0; k < 25; ++k) w[k] = cw[c * 25 + k];
  const float bias = cb[c];

  const float* xp = x + (size_t)bc * LL + lane;
  float* op = xs + (size_t)bc * LL + lane;

  // preload 20 rows (wave-uniform predication; all loads issue up front)
  float rv[20];
#pragma unroll
  for (int r = 0; r < 20; ++r) {
    const int gr = oy0 + r - 2;
    float v = 0.f;
    if ((unsigned)gr < 64u) v = xp[gr * 64];
    rv[r] = v;
  }

  float acc[5];
#pragma unroll
  for (int i = 0; i < 5; ++i) acc[i] = 0.f;

  // input row gr = oy0 + r - 2; output row y = oy0 + (r - ky).
  // y in-wave iff 0 <= r-ky < 16 (static). Row oy0+r-4 completes at iter r.
#pragma unroll
  for (int r = 0; r < 20; ++r) {
    float v = rv[r];
    float vm2 = __shfl_up(v, 2u, 64);
    float vm1 = __shfl_up(v, 1u, 64);
    float vp1 = __shfl_down(v, 1u, 64);
    float vp2 = __shfl_down(v, 2u, 64);
    if (lane < 2) vm2 = 0.f;
    if (lane < 1) vm1 = 0.f;
    if (lane > 62) vp1 = 0.f;
    if (lane > 61) vp2 = 0.f;
    float t[5] = {vm2, vm1, v, vp1, vp2};
#pragma unroll
    for (int ky = 0; ky < 5; ++ky) {
      if (r >= ky && (r - ky) < 16) {        // static under unroll
        float s = acc[(r - ky) % 5];
#pragma unroll
        for (int kx = 0; kx < 5; ++kx) s += w[ky * 5 + kx] * t[kx];
        acc[(r - ky) % 5] = s;
      }
    }
    if (r >= 4) {                            // static under unroll
      const int yf = oy0 + r - 4;
      float a = acc[(r - 4) % 5] + bias;
      op[yf * 64] = silu_f(a);
      acc[(r - 4) % 5] = 0.f;
    }
  }
}

// ---------------------------------------------------------------------------
// K2 (v3): x_dbl[b][k][l] = sum_c x_proj_w[k][c] * xs[b][c][l]
// REDUCTION-FREE: block = 896 threads = 14 waves = KK; wave k accumulates
// its own output row over ALL 192 channels in registers. Zero LDS, zero
// atomics, zero barriers (R5's fp atomicAdd compiled to CAS loops: 89 us
// at 4.6% VALU). All 14 waves stream the same 192x128 tile in near-lockstep
// -> 1 fresh read + 13 L1/L2 hits. Grid (32 strips,16 b) x 14 waves
// = 28 waves/CU; unroll 8 keeps 8 loads in flight per wave.
// ---------------------------------------------------------------------------
__global__ __launch_bounds__(896) void proj_kernel(
    const float* __restrict__ xs, const float* __restrict__ xpw,
    float* __restrict__ xdbl) {
  const int b = blockIdx.y;
  const int l0 = blockIdx.x * 128;
  const int tid = threadIdx.x;
  const int lane = tid & 63;
  const int k = tid >> 6;              // wave id == k, 0..13

  const float* bp = xs + (size_t)b * CC * LL + l0 + lane * 2;
  const float* wp = xpw + k * CC;      // wave-uniform -> scalar loads
  float ax = 0.f, ay = 0.f;
#pragma unroll 8
  for (int c = 0; c < CC; ++c) {
    const float2 v = *(const float2*)(bp + (size_t)c * LL);
    const float w = wp[c];
    ax += w * v.x;
    ay += w * v.y;
  }
  *(float2*)(xdbl + ((size_t)b * KK + k) * LL + l0 + lane * 2) =
      make_float2(ax, ay);
}

// ---------------------------------------------------------------------------
// K3 (v3b): fused dt-projection + softplus + selective scan + output.
// 8 waves per (b,c); wave owns a 512-l segment = 2 chunks of 256 (lane owns
// 4 contiguous l's per chunk — coalesced float4). vs v2 (41.3 us, 4 serial
// chunks each with its own 6-step shuffle scan): serial chain is 2 chunks +
// ONE interleaved 6-step scan (2 independent shuffle chains hide each
// other's DS latency), and 2x the waves (lower VGPR, 24576 waves requested).
//   Phase 1 (per chunk): dt planes consumed incrementally -> z; softplus;
//     a,be; lane-local (P,h) walk; emit alpha = P_local*C,
//     beta = h_local*C + x*D (y = alpha*G_laneentry + beta); chunk agg.
//   Phase 2: both chunks' 6-step wave-scans interleaved in lockstep.
//   Phase 3: chain chunk totals -> per-chunk lane-entry (Pe,he);
//     LDS-exchange 8 wave totals; ordered carry fold (<=7 FMA).
//   Phase 4: G = Pe*carry + he; y = alpha*G + beta; float4 stores.
// ---------------------------------------------------------------------------
__global__ __launch_bounds__(512) void scan_kernel(
    const float* __restrict__ xs, const float* __restrict__ xdbl,
    const float* __restrict__ dtw, const float* __restrict__ dtb,
    const float* __restrict__ A_logs, const float* __restrict__ Ds,
    float* __restrict__ y) {
  const int bc = blockIdx.x;
  const int b = bc / CC;
  const int c = bc - b * CC;
  const int tid = threadIdx.x;
  const int lane = tid & 63;
  const int wv = tid >> 6;  // wave 0..7, owns segment [512*wv, 512*wv+511]

  const float Ac = -__expf(A_logs[c]);  // d_state = 1
  const float Dc = Ds[c];
  float dw[DTR];
#pragma unroll
  for (int r = 0; r < DTR; ++r) dw[r] = dtw[c * DTR + r];
  const float db = dtb[c];

  const float* xp = xs + (size_t)bc * LL;
  const float* xb = xdbl + (size_t)b * KK * LL;
  float* yp = y + (size_t)bc * LL;

  __shared__ float segA[8];
  __shared__ float segB[8];

  float alpha[8], beta[8];     // static indices only (full unroll)
  float aggA[2], aggB[2];

  // ---- phase 1: per-chunk lane-local scan, emit alpha/beta + aggregates ----
#pragma unroll
  for (int ck = 0; ck < 2; ++ck) {
    const int base = wv * 512 + ck * 256 + lane * 4;
    const float4 x4 = *(const float4*)(xp + base);
    const float4 B4 = *(const float4*)(xb + 12 * LL + base);
    const float4 C4 = *(const float4*)(xb + 13 * LL + base);
    // dt-projection consumed incrementally: one dr plane live at a time
    float zx = db, zy = db, zz_ = db, zw = db;
#pragma unroll
    for (int r = 0; r < DTR; ++r) {
      const float4 d4 = *(const float4*)(xb + r * LL + base);
      zx += dw[r] * d4.x;
      zy += dw[r] * d4.y;
      zz_ += dw[r] * d4.z;
      zw += dw[r] * d4.w;
    }
    const float zq[4] = {zx, zy, zz_, zw};
    float Pl = 1.f, hl = 0.f;
#pragma unroll
    for (int q = 0; q < 4; ++q) {
      const float z = zq[q];
      const float delta = (z > 15.f) ? z : __logf(1.f + __expf(z));
      const float a = __expf(delta * Ac);
      const float be = delta * ((&B4.x)[q]) * ((&x4.x)[q]);
      hl = a * hl + be;
      Pl = Pl * a;
      alpha[ck * 4 + q] = Pl * ((&C4.x)[q]);
      beta[ck * 4 + q] = hl * ((&C4.x)[q]) + ((&x4.x)[q]) * Dc;
    }
    aggA[ck] = Pl;
    aggB[ck] = hl;
  }

  // ---- phase 2: both chunk wave-scans interleaved in lockstep ----
  float iA[2], iB[2];
#pragma unroll
  for (int ck = 0; ck < 2; ++ck) { iA[ck] = aggA[ck]; iB[ck] = aggB[ck]; }
#pragma unroll
  for (int s = 1; s < 64; s <<= 1) {
    float pA[2], pB[2];
#pragma unroll
    for (int ck = 0; ck < 2; ++ck) {
      pA[ck] = __shfl_up(iA[ck], (unsigned)s, 64);
      pB[ck] = __shfl_up(iB[ck], (unsigned)s, 64);
    }
    if (lane >= s) {
#pragma unroll
      for (int ck = 0; ck < 2; ++ck) {
        iB[ck] = iA[ck] * pB[ck] + iB[ck];
        iA[ck] = iA[ck] * pA[ck];
      }
    }
  }
  float eA[2], eB[2], tA[2], tB[2];
#pragma unroll
  for (int ck = 0; ck < 2; ++ck) {
    eA[ck] = __shfl_up(iA[ck], 1u, 64);
    eB[ck] = __shfl_up(iB[ck], 1u, 64);
    if (lane == 0) { eA[ck] = 1.f; eB[ck] = 0.f; }
    tA[ck] = __shfl(iA[ck], 63, 64);
    tB[ck] = __shfl(iB[ck], 63, 64);
  }

  // ---- phase 3: chain chunk totals; lane-entry (Pe,he) per chunk ----
  float Pe[2], he[2];
  float SP = 1.f, Sh = 0.f;   // segment state at current chunk entry
#pragma unroll
  for (int ck = 0; ck < 2; ++ck) {
    Pe[ck] = SP * eA[ck];
    he[ck] = eA[ck] * Sh + eB[ck];
    Sh = tA[ck] * Sh + tB[ck];
    SP = SP * tA[ck];
  }

  if (lane == 0) { segA[wv] = SP; segB[wv] = Sh; }
  __syncthreads();
  float carry = 0.f;
  for (int i = 0; i < wv; ++i) carry = segA[i] * carry + segB[i];

  // ---- phase 4: epilogue ----
#pragma unroll
  for (int ck = 0; ck < 2; ++ck) {
    const float G = Pe[ck] * carry + he[ck];
    const int base = wv * 512 + ck * 256 + lane * 4;
    float4 o;
    o.x = alpha[ck * 4 + 0] * G + beta[ck * 4 + 0];
    o.y = alpha[ck * 4 + 1] * G + beta[ck * 4 + 1];
    o.z = alpha[ck * 4 + 2] * G + beta[ck * 4 + 2];
    o.w = alpha[ck * 4 + 3] * G + beta[ck * 4 + 3];
    *(float4*)(yp + base) = o;
  }
}

// ---------------------------------------------------------------------------
extern "C" void kernel_launch(void* const* d_in, const int* in_sizes, int n_in,
                              void* d_out, int out_size, void* d_ws,
                              size_t ws_size, hipStream_t stream) {
  const float* x        = (const float*)d_in[0];
  const float* conv_w   = (const float*)d_in[1];
  const float* conv_b   = (const float*)d_in[2];
  const float* x_proj_w = (const float*)d_in[3];
  const float* dt_w     = (const float*)d_in[4];
  const float* dt_b     = (const float*)d_in[5];
  const float* A_logs   = (const float*)d_in[6];
  const float* Ds       = (const float*)d_in[7];
  float* out = (float*)d_out;

  char* ws = (char*)d_ws;
  const size_t plane_bytes = (size_t)BB * CC * LL * sizeof(float);  // 50.3 MB
  float* xs   = (float*)ws;
  float* xdbl = (float*)(ws + plane_bytes);  // BB*KK*LL floats = 3.67 MB

  conv_silu_kernel<<<dim3(BB * CC), 256, 0, stream>>>(x, conv_w, conv_b, xs);
  proj_kernel<<<dim3(LL / 128, BB), 896, 0, stream>>>(xs, x_proj_w, xdbl);
  scan_kernel<<<dim3(BB * CC), 512, 0, stream>>>(xs, xdbl, dt_w, dt_b,
                                                 A_logs, Ds, out);
}

// Round 8
// 174.857 us; speedup vs baseline: 1.3728x; 1.1715x over previous
//
#include <hip/hip_runtime.h>
#include <hip/hip_bf16.h>
#include <cstddef>

// Problem constants (from reference setup_inputs)
#define BB 16
#define CC 192
#define HH 64
#define WW 64
#define LL 4096   // H*W
#define DTR 12    // dt_rank
#define KK 14     // dt_rank + 2*d_state, d_state = 1
#define NSL 8     // c-slices in proj (24 channels each)

__device__ __forceinline__ float silu_f(float v) {
  return v / (1.f + __expf(-v));
}

// ---------------------------------------------------------------------------
// K1: depthwise 5x5 conv (SAME, zero pad) + bias + SiLU — LDS-free.
// One block (4 waves) per (b,c) plane; wave w owns output rows 16w..16w+15.
// Lane = x column. PRELOAD all 20 input rows (2-row halo each side) into
// registers (20 loads in flight), then: 4 shuffles per row + ring of 5
// output-row accumulators with static indices.  (known-good, unchanged)
// ---------------------------------------------------------------------------
__global__ __launch_bounds__(256) void conv_silu_kernel(
    const float* __restrict__ x, const float* __restrict__ cw,
    const float* __restrict__ cb, float* __restrict__ xs) {
  const int bc = blockIdx.x;           // b*CC + c
  const int c = bc % CC;
  const int tid = threadIdx.x;
  const int lane = tid & 63;           // x column 0..63
  const int wv = tid >> 6;             // wave 0..3
  const int oy0 = wv * 16;             // first output row of this wave

  float w[25];
#pragma unroll
  for (int k = 0; k < 25; ++k) w[k] = cw[c * 25 + k];
  const float bias = cb[c];

  const float* xp = x + (size_t)bc * LL + lane;
  float* op = xs + (size_t)bc * LL + lane;

  // preload 20 rows (wave-uniform predication; all loads issue up front)
  float rv[20];
#pragma unroll
  for (int r = 0; r < 20; ++r) {
    const int gr = oy0 + r - 2;
    float v = 0.f;
    if ((unsigned)gr < 64u) v = xp[gr * 64];
    rv[r] = v;
  }

  float acc[5];
#pragma unroll
  for (int i = 0; i < 5; ++i) acc[i] = 0.f;

  // input row gr = oy0 + r - 2; output row y = oy0 + (r - ky).
  // y in-wave iff 0 <= r-ky < 16 (static). Row oy0+r-4 completes at iter r.
#pragma unroll
  for (int r = 0; r < 20; ++r) {
    float v = rv[r];
    float vm2 = __shfl_up(v, 2u, 64);
    float vm1 = __shfl_up(v, 1u, 64);
    float vp1 = __shfl_down(v, 1u, 64);
    float vp2 = __shfl_down(v, 2u, 64);
    if (lane < 2) vm2 = 0.f;
    if (lane < 1) vm1 = 0.f;
    if (lane > 62) vp1 = 0.f;
    if (lane > 61) vp2 = 0.f;
    float t[5] = {vm2, vm1, v, vp1, vp2};
#pragma unroll
    for (int ky = 0; ky < 5; ++ky) {
      if (r >= ky && (r - ky) < 16) {        // static under unroll
        float s = acc[(r - ky) % 5];
#pragma unroll
        for (int kx = 0; kx < 5; ++kx) s += w[ky * 5 + kx] * t[kx];
        acc[(r - ky) % 5] = s;
      }
    }
    if (r >= 4) {                            // static under unroll
      const int yf = oy0 + r - 4;
      float a = acc[(r - 4) % 5] + bias;
      op[yf * 64] = silu_f(a);
      acc[(r - 4) % 5] = 0.f;
    }
  }
}

// ---------------------------------------------------------------------------
// K2a (v4): partial projection. part[b][sl][k][l] = sum over this slice's
// 24 channels of x_proj_w[k][c] * xs[b][c][l].
// ONE WAVE per block; wave owns (b, slice of 24 c, 256-l strip). Per thread:
// 24 float4 loads (unroll 6 -> 6 KB/wave in flight), 14 wave-uniform scalar
// weight loads per channel, acc[14] x float4 in regs, coalesced float4
// stores. No LDS, no atomics, no barriers; xs read exactly once per block
// (the v3 wave-per-k kernel re-read each tile 14x from L2: 53.5 us at
// 13% VALU, 23 cyc/load exposed latency).
// ---------------------------------------------------------------------------
__global__ __launch_bounds__(64) void proj_part_kernel(
    const float* __restrict__ xs, const float* __restrict__ xpw,
    float* __restrict__ part) {
  const int l0 = blockIdx.x * 256;
  const int b = blockIdx.y;
  const int sl = blockIdx.z;           // slice 0..7
  const int lane = threadIdx.x;        // 0..63
  const int c0 = sl * 24;

  float4 acc[KK];
#pragma unroll
  for (int k = 0; k < KK; ++k) acc[k] = make_float4(0.f, 0.f, 0.f, 0.f);

  const float* bp = xs + ((size_t)(b * CC + c0)) * LL + l0 + lane * 4;
#pragma unroll 6
  for (int cc = 0; cc < 24; ++cc) {
    const float4 v = *(const float4*)(bp + (size_t)cc * LL);
    const int c = c0 + cc;             // wave-uniform -> scalar weight loads
#pragma unroll
    for (int k = 0; k < KK; ++k) {
      const float w = xpw[k * CC + c];
      acc[k].x += w * v.x;
      acc[k].y += w * v.y;
      acc[k].z += w * v.z;
      acc[k].w += w * v.w;
    }
  }

  float* pp = part + ((size_t)((b * NSL + sl) * KK)) * LL + l0 + lane * 4;
#pragma unroll
  for (int k = 0; k < KK; ++k)
    *(float4*)(pp + (size_t)k * LL) = acc[k];
}

// ---------------------------------------------------------------------------
// K2b: reduce the 8 slice-partials: xdbl[b][k][l] = sum_s part[b][s][k][l].
// Pure stream: 8 float4 loads + 7 adds + 1 float4 store per thread.
// Grid (4 l-chunks, KK, BB) x 256 thr = 3584 waves.
// ---------------------------------------------------------------------------
__global__ __launch_bounds__(256) void proj_reduce_kernel(
    const float* __restrict__ part, float* __restrict__ xdbl) {
  const int f = blockIdx.x * 256 + threadIdx.x;   // float4 index 0..1023
  const int k = blockIdx.y;
  const int b = blockIdx.z;
  const size_t off = (size_t)f * 4;

  float4 s = make_float4(0.f, 0.f, 0.f, 0.f);
#pragma unroll
  for (int sl = 0; sl < NSL; ++sl) {
    const float4 v = *(const float4*)(
        part + ((size_t)((b * NSL + sl) * KK + k)) * LL + off);
    s.x += v.x; s.y += v.y; s.z += v.z; s.w += v.w;
  }
  *(float4*)(xdbl + ((size_t)(b * KK + k)) * LL + off) = s;
}

// ---------------------------------------------------------------------------
// K3 (v3b): fused dt-projection + softplus + selective scan + output.
// 8 waves per (b,c); wave owns a 512-l segment = 2 chunks of 256 (lane owns
// 4 contiguous l's per chunk — coalesced float4). Serial chain: 2 chunks +
// ONE interleaved 6-step shuffle scan; 8-float LDS wave-total exchange.
// (unchanged this round)
// ---------------------------------------------------------------------------
__global__ __launch_bounds__(512) void scan_kernel(
    const float* __restrict__ xs, const float* __restrict__ xdbl,
    const float* __restrict__ dtw, const float* __restrict__ dtb,
    const float* __restrict__ A_logs, const float* __restrict__ Ds,
    float* __restrict__ y) {
  const int bc = blockIdx.x;
  const int b = bc / CC;
  const int c = bc - b * CC;
  const int tid = threadIdx.x;
  const int lane = tid & 63;
  const int wv = tid >> 6;  // wave 0..7, owns segment [512*wv, 512*wv+511]

  const float Ac = -__expf(A_logs[c]);  // d_state = 1
  const float Dc = Ds[c];
  float dw[DTR];
#pragma unroll
  for (int r = 0; r < DTR; ++r) dw[r] = dtw[c * DTR + r];
  const float db = dtb[c];

  const float* xp = xs + (size_t)bc * LL;
  const float* xb = xdbl + (size_t)b * KK * LL;
  float* yp = y + (size_t)bc * LL;

  __shared__ float segA[8];
  __shared__ float segB[8];

  float alpha[8], beta[8];     // static indices only (full unroll)
  float aggA[2], aggB[2];

  // ---- phase 1: per-chunk lane-local scan, emit alpha/beta + aggregates ----
#pragma unroll
  for (int ck = 0; ck < 2; ++ck) {
    const int base = wv * 512 + ck * 256 + lane * 4;
    const float4 x4 = *(const float4*)(xp + base);
    const float4 B4 = *(const float4*)(xb + 12 * LL + base);
    const float4 C4 = *(const float4*)(xb + 13 * LL + base);
    // dt-projection consumed incrementally: one dr plane live at a time
    float zx = db, zy = db, zz_ = db, zw = db;
#pragma unroll
    for (int r = 0; r < DTR; ++r) {
      const float4 d4 = *(const float4*)(xb + r * LL + base);
      zx += dw[r] * d4.x;
      zy += dw[r] * d4.y;
      zz_ += dw[r] * d4.z;
      zw += dw[r] * d4.w;
    }
    const float zq[4] = {zx, zy, zz_, zw};
    float Pl = 1.f, hl = 0.f;
#pragma unroll
    for (int q = 0; q < 4; ++q) {
      const float z = zq[q];
      const float delta = (z > 15.f) ? z : __logf(1.f + __expf(z));
      const float a = __expf(delta * Ac);
      const float be = delta * ((&B4.x)[q]) * ((&x4.x)[q]);
      hl = a * hl + be;
      Pl = Pl * a;
      alpha[ck * 4 + q] = Pl * ((&C4.x)[q]);
      beta[ck * 4 + q] = hl * ((&C4.x)[q]) + ((&x4.x)[q]) * Dc;
    }
    aggA[ck] = Pl;
    aggB[ck] = hl;
  }

  // ---- phase 2: both chunk wave-scans interleaved in lockstep ----
  float iA[2], iB[2];
#pragma unroll
  for (int ck = 0; ck < 2; ++ck) { iA[ck] = aggA[ck]; iB[ck] = aggB[ck]; }
#pragma unroll
  for (int s = 1; s < 64; s <<= 1) {
    float pA[2], pB[2];
#pragma unroll
    for (int ck = 0; ck < 2; ++ck) {
      pA[ck] = __shfl_up(iA[ck], (unsigned)s, 64);
      pB[ck] = __shfl_up(iB[ck], (unsigned)s, 64);
    }
    if (lane >= s) {
#pragma unroll
      for (int ck = 0; ck < 2; ++ck) {
        iB[ck] = iA[ck] * pB[ck] + iB[ck];
        iA[ck] = iA[ck] * pA[ck];
      }
    }
  }
  float eA[2], eB[2], tA[2], tB[2];
#pragma unroll
  for (int ck = 0; ck < 2; ++ck) {
    eA[ck] = __shfl_up(iA[ck], 1u, 64);
    eB[ck] = __shfl_up(iB[ck], 1u, 64);
    if (lane == 0) { eA[ck] = 1.f; eB[ck] = 0.f; }
    tA[ck] = __shfl(iA[ck], 63, 64);
    tB[ck] = __shfl(iB[ck], 63, 64);
  }

  // ---- phase 3: chain chunk totals; lane-entry (Pe,he) per chunk ----
  float Pe[2], he[2];
  float SP = 1.f, Sh = 0.f;   // segment state at current chunk entry
#pragma unroll
  for (int ck = 0; ck < 2; ++ck) {
    Pe[ck] = SP * eA[ck];
    he[ck] = eA[ck] * Sh + eB[ck];
    Sh = tA[ck] * Sh + tB[ck];
    SP = SP * tA[ck];
  }

  if (lane == 0) { segA[wv] = SP; segB[wv] = Sh; }
  __syncthreads();
  float carry = 0.f;
  for (int i = 0; i < wv; ++i) carry = segA[i] * carry + segB[i];

  // ---- phase 4: epilogue ----
#pragma unroll
  for (int ck = 0; ck < 2; ++ck) {
    const float G = Pe[ck] * carry + he[ck];
    const int base = wv * 512 + ck * 256 + lane * 4;
    float4 o;
    o.x = alpha[ck * 4 + 0] * G + beta[ck * 4 + 0];
    o.y = alpha[ck * 4 + 1] * G + beta[ck * 4 + 1];
    o.z = alpha[ck * 4 + 2] * G + beta[ck * 4 + 2];
    o.w = alpha[ck * 4 + 3] * G + beta[ck * 4 + 3];
    *(float4*)(yp + base) = o;
  }
}

// ---------------------------------------------------------------------------
extern "C" void kernel_launch(void* const* d_in, const int* in_sizes, int n_in,
                              void* d_out, int out_size, void* d_ws,
                              size_t ws_size, hipStream_t stream) {
  const float* x        = (const float*)d_in[0];
  const float* conv_w   = (const float*)d_in[1];
  const float* conv_b   = (const float*)d_in[2];
  const float* x_proj_w = (const float*)d_in[3];
  const float* dt_w     = (const float*)d_in[4];
  const float* dt_b     = (const float*)d_in[5];
  const float* A_logs   = (const float*)d_in[6];
  const float* Ds       = (const float*)d_in[7];
  float* out = (float*)d_out;

  char* ws = (char*)d_ws;
  const size_t plane_bytes = (size_t)BB * CC * LL * sizeof(float);     // 50.3 MB
  const size_t xdbl_bytes  = (size_t)BB * KK * LL * sizeof(float);     // 3.67 MB
  float* xs   = (float*)ws;
  float* xdbl = (float*)(ws + plane_bytes);
  float* part = (float*)(ws + plane_bytes + xdbl_bytes);               // 29.4 MB

  conv_silu_kernel<<<dim3(BB * CC), 256, 0, stream>>>(x, conv_w, conv_b, xs);
  proj_part_kernel<<<dim3(LL / 256, BB, NSL), 64, 0, stream>>>(
      xs, x_proj_w, part);
  proj_reduce_kernel<<<dim3(LL / 4 / 256, KK, BB), 256, 0, stream>>>(
      part, xdbl);
  scan_kernel<<<dim3(BB * CC), 512, 0, stream>>>(xs, xdbl, dt_w, dt_b,
                                                 A_logs, Ds, out);
}